// Round 16
// baseline (77.554 us; speedup 1.0000x reference)
//
#include <hip/hip_runtime.h>
#include <stdint.h>

#define HW 3136
#define IMGW 56
#define NIMG 32

typedef int i32x4 __attribute__((ext_vector_type(4)));

// BN: round((alpha*acc + off) * 2^-10), clamp to [-128,127]. Exact f32 ops,
// no contraction (matches numpy mul/add/round-half-even chain bit-exactly).
static __device__ __forceinline__ float bnq(float alpha, float off, int acc) {
  float t = __fmul_rn(alpha, (float)acc);
  t = __fadd_rn(t, off);
  t = __fmul_rn(t, 0x1p-10f);
  float r = rintf(t);
  return fminf(fmaxf(r, -128.0f), 127.0f);
}

// ---------------- prep: pack weights into MFMA B-fragments + fold BN ----------------
// (identical layouts to R15 — verified absmax 0)
__global__ void prep_kernel(
    const int* __restrict__ s1, const int* __restrict__ m1,
    const float* __restrict__ a1, const float* __restrict__ b1, const int* __restrict__ q1,
    const int* __restrict__ s2, const int* __restrict__ m2,
    const float* __restrict__ a2, const float* __restrict__ b2, const int* __restrict__ q2,
    const int* __restrict__ s3, const int* __restrict__ m3,
    const float* __restrict__ a3, const float* __restrict__ b3, const int* __restrict__ q3,
    int* __restrict__ w1m, int* __restrict__ w2m, int* __restrict__ w3m,
    float* __restrict__ a1p, float* __restrict__ o1p,
    float* __restrict__ a2p, float* __restrict__ o2p,
    float* __restrict__ a3p, float* __restrict__ o3p)
{
  int t = blockIdx.x * blockDim.x + threadIdx.x;
  int nthr = gridDim.x * blockDim.x;

  // w1m[((kk*4+s)*64+l)*4+jw]: conv1 B-frag, K-step kk (ci kk*64..+63), co=s*16+(l&15)
  for (int i = t; i < 4096; i += nthr) {
    int jw = i & 3, l = (i >> 2) & 63;
    int rest = i >> 8;              // kk*4+s
    int s = rest & 3, kk = rest >> 2;
    int c = l & 15, g = l >> 4;
    int co = s * 16 + c;
    int p = 0;
    for (int b = 0; b < 4; ++b) {
      int ci = kk * 64 + g * 16 + jw * 4 + b;
      int idx = co * 256 + ci;
      int w = m1[idx] * (1 << s1[idx]);
      p |= (w & 0xFF) << (8 * b);
    }
    w1m[i] = p;
  }
  // w2m[((tap*4+s)*64+l)*4+jw]: conv2 B-frag per tap
  for (int i = t; i < 9216; i += nthr) {
    int jw = i & 3, l = (i >> 2) & 63;
    int rest = i >> 8;              // tap*4+s
    int s = rest & 3, tap = rest >> 2;
    int c = l & 15, g = l >> 4;
    int co = s * 16 + c;
    int ky = tap / 3, kx = tap - ky * 3;
    int p = 0;
    for (int b = 0; b < 4; ++b) {
      int ci = g * 16 + jw * 4 + b;
      int idx = ((co * 64 + ci) * 3 + ky) * 3 + kx;
      int w = m2[idx] * (1 << s2[idx]);
      p |= (w & 0xFF) << (8 * b);
    }
    w2m[i] = p;
  }
  // w3m[((s*4+nt)*64+l)*4+jw]: conv3 B-frag, co=s*64+nt*16+(l&15)
  for (int i = t; i < 4096; i += nthr) {
    int jw = i & 3, l = (i >> 2) & 63;
    int rest = i >> 8;              // s*4+nt
    int nt = rest & 3, s = rest >> 2;
    int c = l & 15, g = l >> 4;
    int co = s * 64 + nt * 16 + c;
    int p = 0;
    for (int b = 0; b < 4; ++b) {
      int ci = g * 16 + jw * 4 + b;
      int idx = co * 64 + ci;
      int w = m3[idx] * (1 << s3[idx]);
      p |= (w & 0xFF) << (8 * b);
    }
    w3m[i] = p;
  }
  for (int i = t; i < 64; i += nthr) {
    a1p[i] = a1[i];
    o1p[i] = __fmul_rn(b1[i], exp2f((float)q1[i] + 10.0f));
    a2p[i] = a2[i];
    o2p[i] = __fmul_rn(b2[i], exp2f((float)q2[i] + 10.0f));
  }
  for (int i = t; i < 256; i += nthr) {
    a3p[i] = a3[i];
    o3p[i] = __fmul_rn(b3[i], exp2f((float)q3[i] + 10.0f));
  }
}

// ---------------- kfused: pack -> conv1(halo recompute) -> conv2 -> conv3 ----------------
// Block = 64 out positions (2 image rows). Packs x and runs conv1 over the FULL
// 232-pos halo (4 rows x 58, zero-padded) in LDS -> conv2 needs no global y1;
// residual int8 grabbed from packed-x LDS -> no x8p. Two K-halves of x staging
// keep LDS at 53.1 KB -> 3 blocks/CU. HBM = x read + out write only.
__global__ __launch_bounds__(256) void kfused(
    const float* __restrict__ x,
    const int* __restrict__ w1m, const float* __restrict__ a1p, const float* __restrict__ o1p,
    const int* __restrict__ w2m, const float* __restrict__ a2p, const float* __restrict__ o2p,
    const int* __restrict__ w3m, const float* __restrict__ a3p, const float* __restrict__ o3p,
    float* __restrict__ out)
{
  __shared__ __align__(16) char smem[53120];
  int*  xt  = (int*)smem;          // [240][36] ints = 34560 B (dead after conv1)
  char* y1t = smem + 34560;        // [232][80 B] = 18560 B
  char* y2t = smem;                // [64][80 B] = 5120 B (aliases dead xt)
  // Dw: per-wave [64][20] ints at smem+5120+sW*5120 (aliases dead xt)

  // bijective XCD swizzle: XCD k runs tiles 196k..196k+195 (1568 = 8*196)
  int t0 = (blockIdx.x & 7) * 196 + (blockIdx.x >> 3);
  int n = t0 / 49, bl = t0 - n * 49;
  int p0l = bl * 64;
  int h0 = p0l / IMGW;

  int tid = threadIdx.x;
  int lane = tid & 63;
  int sW = __builtin_amdgcn_readfirstlane(tid >> 6);
  int c = lane & 15, g = lane >> 4;

  // pack geometry: thread = one padded halo position pp
  int pp = tid;
  int r58 = pp / 58, col = pp - r58 * 58;
  int phh = h0 - 1 + r58, pww = col - 1;
  bool pvalid = (pp < 232) && ((unsigned)phh < 56u) && ((unsigned)pww < 56u);
  const float* xb = x + (size_t)n * 256 * HW + phh * IMGW + pww;

  // residual source row (center position of this lane)
  int P = p0l + lane;
  int hP = P / IMGW, wP = P - hP * IMGW;
  int ppc = (hP - h0 + 1) * 58 + wP + 1;

  i32x4 acc1[15];
#pragma unroll
  for (int i = 0; i < 15; ++i) acc1[i] = (i32x4){0, 0, 0, 0};
  i32x4 rq0 = (i32x4){0,0,0,0}, rq1 = rq0, rq2 = rq0, rq3 = rq0;

#pragma unroll
  for (int hf = 0; hf < 2; ++hf) {
    // ---- pack K-half hf (channels hf*128..+127) -> xt[pp][0..31] ----
    if (pvalid) {
#pragma unroll
      for (int bb = 0; bb < 2; ++bb) {
        float f[64];
#pragma unroll
        for (int k = 0; k < 64; ++k)
          f[k] = xb[(size_t)(hf * 128 + bb * 64 + k) * HW];
        __builtin_amdgcn_sched_barrier(0);  // 64 loads in flight (k0 pattern)
#pragma unroll
        for (int w = 0; w < 16; ++w) {
          int wd = ((int)f[w * 4] & 0xFF) | (((int)f[w * 4 + 1] & 0xFF) << 8) |
                   (((int)f[w * 4 + 2] & 0xFF) << 16) | (((int)f[w * 4 + 3] & 0xFF) << 24);
          xt[pp * 36 + bb * 16 + w] = wd;
        }
      }
    } else if (pp < 240) {
#pragma unroll
      for (int w = 0; w < 32; ++w) xt[pp * 36 + w] = 0;
    }
    __syncthreads();

    // residual grab: wave sW owns words sW*16..+15, located in half sW>>1
    if ((sW >> 1) == hf) {
      int bw = (sW & 1) * 16;
      rq0 = *(const i32x4*)(xt + ppc * 36 + bw + 0);
      rq1 = *(const i32x4*)(xt + ppc * 36 + bw + 4);
      rq2 = *(const i32x4*)(xt + ppc * 36 + bw + 8);
      rq3 = *(const i32x4*)(xt + ppc * 36 + bw + 12);
    }

    // conv1 partial: 2 global K-steps over 15 M-tiles
#pragma unroll
    for (int kk = 0; kk < 2; ++kk) {
      int kkg = hf * 2 + kk;
      i32x4 bf = *(const i32x4*)(w1m + ((kkg * 4 + sW) * 64 + lane) * 4);
#pragma unroll
      for (int mt = 0; mt < 15; ++mt) {
        i32x4 af = *(const i32x4*)(xt + (mt * 16 + c) * 36 + kk * 16 + g * 4);
        acc1[mt] = __builtin_amdgcn_mfma_i32_16x16x64_i8(af, bf, acc1[mt], 0, 0, 0);
      }
    }
    __syncthreads();   // xt reads done before next half overwrites
  }

  // ---- conv1 BN+relu -> y1t; zero out-of-image positions (conv2 padding) ----
  {
    float al = a1p[sW * 16 + c], of = o1p[sW * 16 + c];
#pragma unroll
    for (int mt = 0; mt < 15; ++mt) {
#pragma unroll
      for (int r = 0; r < 4; ++r) {
        int prow = mt * 16 + g * 4 + r;
        if (prow < 232) {      // compile-time for mt<14; runtime guard on mt=14
          int pr = prow / 58, pc = prow - pr * 58;
          int ph = h0 - 1 + pr;
          bool pv = ((unsigned)ph < 56u) && (pc >= 1) && (pc <= 56);
          float rv = bnq(al, of, acc1[mt][r]);
          int v = (int)rv;
          if (v < 0) v = 0;
          y1t[prow * 80 + sW * 16 + c] = pv ? (char)v : (char)0;
        }
      }
    }
  }
  __syncthreads();

  // ---- conv2: 9 taps x 4 M-tiles from y1t ----
  int cen[4];
#pragma unroll
  for (int mt = 0; mt < 4; ++mt) {
    int pos = p0l + mt * 16 + c;
    int hh2 = pos / IMGW, ww2 = pos - hh2 * IMGW;
    cen[mt] = (hh2 - h0 + 1) * 58 + ww2 + 1;
  }

  i32x4 acc2[4];
#pragma unroll
  for (int i = 0; i < 4; ++i) acc2[i] = (i32x4){0, 0, 0, 0};

#pragma unroll
  for (int tap = 0; tap < 9; ++tap) {
    i32x4 bf = *(const i32x4*)(w2m + ((tap * 4 + sW) * 64 + lane) * 4);
    int ky = tap / 3, kx = tap - ky * 3;
    int d = (ky - 1) * 58 + (kx - 1);
#pragma unroll
    for (int mt = 0; mt < 4; ++mt) {
      i32x4 af = *(const i32x4*)(y1t + (cen[mt] + d) * 80 + g * 16);
      acc2[mt] = __builtin_amdgcn_mfma_i32_16x16x64_i8(af, bf, acc2[mt], 0, 0, 0);
    }
  }

  // ---- conv2 BN+relu -> y2t (aliases dead xt region) ----
  {
    float al = a2p[sW * 16 + c], of = o2p[sW * 16 + c];
#pragma unroll
    for (int mt = 0; mt < 4; ++mt) {
#pragma unroll
      for (int r = 0; r < 4; ++r) {
        float rv = bnq(al, of, acc2[mt][r]);
        int v = (int)rv;
        if (v < 0) v = 0;
        y2t[(mt * 16 + g * 4 + r) * 80 + sW * 16 + c] = (char)v;
      }
    }
  }
  __syncthreads();

  // ---- conv3 MFMA + transpose-through-LDS epilogue (R15 structure) ----
  int* Dw = (int*)(smem + 5120) + sW * 1280;   // per-wave [64 pos][20 ints]
  int posl = p0l + lane;
  float* ob = out + (size_t)n * 256 * HW + posl;

#pragma unroll
  for (int nt = 0; nt < 4; ++nt) {
    i32x4 bf = *(const i32x4*)(w3m + ((sW * 4 + nt) * 64 + lane) * 4);
#pragma unroll
    for (int mt = 0; mt < 4; ++mt) {
      i32x4 af = *(const i32x4*)(y2t + (mt * 16 + c) * 80 + g * 16);
      i32x4 z = {0, 0, 0, 0};
      i32x4 D = __builtin_amdgcn_mfma_i32_16x16x64_i8(af, bf, z, 0, 0, 0);
      Dw[(mt * 16 + g * 4 + 0) * 20 + c] = D[0];
      Dw[(mt * 16 + g * 4 + 1) * 20 + c] = D[1];
      Dw[(mt * 16 + g * 4 + 2) * 20 + c] = D[2];
      Dw[(mt * 16 + g * 4 + 3) * 20 + c] = D[3];
    }
    // same-wave LDS write->read: ordered via lgkmcnt (compiler-inserted)
    i32x4 q0 = *(const i32x4*)(Dw + lane * 20 + 0);
    i32x4 q1 = *(const i32x4*)(Dw + lane * 20 + 4);
    i32x4 q2 = *(const i32x4*)(Dw + lane * 20 + 8);
    i32x4 q3 = *(const i32x4*)(Dw + lane * 20 + 12);
    i32x4 rqn = nt == 0 ? rq0 : (nt == 1 ? rq1 : (nt == 2 ? rq2 : rq3));
#pragma unroll
    for (int cc = 0; cc < 16; ++cc) {
      int accv = cc < 4 ? q0[cc] : cc < 8 ? q1[cc - 4] : cc < 12 ? q2[cc - 8] : q3[cc - 12];
      int co = sW * 64 + nt * 16 + cc;            // wave-uniform -> s_load BN consts
      float rv = bnq(a3p[co], o3p[co], accv);
      int ip = rqn[cc >> 2];
      int id = (int)(int8_t)(ip >> (8 * (cc & 3)));
      int v = (int)rv + id;
      v = v > 127 ? 127 : v;
      v = v < 0 ? 0 : v;  // clamp(-128,..) then relu => max(0, min(127, .))
      ob[(size_t)co * HW] = (float)v;
    }
  }
}

extern "C" void kernel_launch(void* const* d_in, const int* in_sizes, int n_in,
                              void* d_out, int out_size, void* d_ws, size_t ws_size,
                              hipStream_t stream) {
  const float* x  = (const float*)d_in[0];
  const int*   s1 = (const int*)d_in[1];
  const int*   m1 = (const int*)d_in[2];
  const float* a1 = (const float*)d_in[3];
  const float* b1 = (const float*)d_in[4];
  const int*   q1 = (const int*)d_in[5];
  const int*   s2 = (const int*)d_in[6];
  const int*   m2 = (const int*)d_in[7];
  const float* a2 = (const float*)d_in[8];
  const float* b2 = (const float*)d_in[9];
  const int*   q2 = (const int*)d_in[10];
  const int*   s3 = (const int*)d_in[11];
  const int*   m3 = (const int*)d_in[12];
  const float* a3 = (const float*)d_in[13];
  const float* b3 = (const float*)d_in[14];
  const int*   q3 = (const int*)d_in[15];

  char* ws = (char*)d_ws;
  int* w1m = (int*)(ws + 0);        // 16384 B
  int* w2m = (int*)(ws + 16384);    // 36864 B
  int* w3m = (int*)(ws + 53248);    // 16384 B
  float* a1p = (float*)(ws + 69632);
  float* o1p = (float*)(ws + 69888);
  float* a2p = (float*)(ws + 70144);
  float* o2p = (float*)(ws + 70400);
  float* a3p = (float*)(ws + 70656);
  float* o3p = (float*)(ws + 71680);

  prep_kernel<<<64, 256, 0, stream>>>(s1, m1, a1, b1, q1,
                                      s2, m2, a2, b2, q2,
                                      s3, m3, a3, b3, q3,
                                      w1m, w2m, w3m,
                                      a1p, o1p, a2p, o2p, a3p, o3p);

  kfused<<<(NIMG * HW) / 64, 256, 0, stream>>>(
      x, w1m, a1p, o1p, w2m, a2p, o2p, w3m, a3p, o3p, (float*)d_out);
}

// Round 17
// 69.605 us; speedup vs baseline: 1.1142x; 1.1142x over previous
//
#include <hip/hip_runtime.h>
#include <stdint.h>

#define HW 3136
#define IMGW 56
#define NIMG 32

typedef int i32x4 __attribute__((ext_vector_type(4)));

// BN: round((alpha*acc + off) * 2^-10), clamp to [-128,127]. Exact f32 ops,
// no contraction (matches numpy mul/add/round-half-even chain bit-exactly).
static __device__ __forceinline__ float bnq(float alpha, float off, int acc) {
  float t = __fmul_rn(alpha, (float)acc);
  t = __fadd_rn(t, off);
  t = __fmul_rn(t, 0x1p-10f);
  float r = rintf(t);
  return fminf(fmaxf(r, -128.0f), 127.0f);
}

// ---------------- prep: pack weights into MFMA B-fragments + fold BN ----------------
// (identical layouts to R15 — verified absmax 0)
__global__ void prep_kernel(
    const int* __restrict__ s1, const int* __restrict__ m1,
    const float* __restrict__ a1, const float* __restrict__ b1, const int* __restrict__ q1,
    const int* __restrict__ s2, const int* __restrict__ m2,
    const float* __restrict__ a2, const float* __restrict__ b2, const int* __restrict__ q2,
    const int* __restrict__ s3, const int* __restrict__ m3,
    const float* __restrict__ a3, const float* __restrict__ b3, const int* __restrict__ q3,
    int* __restrict__ w1m, int* __restrict__ w2m, int* __restrict__ w3m,
    float* __restrict__ a1p, float* __restrict__ o1p,
    float* __restrict__ a2p, float* __restrict__ o2p,
    float* __restrict__ a3p, float* __restrict__ o3p)
{
  int t = blockIdx.x * blockDim.x + threadIdx.x;
  int nthr = gridDim.x * blockDim.x;

  // w1m[((kk*4+s)*64+l)*4+jw]: conv1 B-frag, K-step kk (ci kk*64..+63), co=s*16+(l&15)
  for (int i = t; i < 4096; i += nthr) {
    int jw = i & 3, l = (i >> 2) & 63;
    int rest = i >> 8;              // kk*4+s
    int s = rest & 3, kk = rest >> 2;
    int c = l & 15, g = l >> 4;
    int co = s * 16 + c;
    int p = 0;
    for (int b = 0; b < 4; ++b) {
      int ci = kk * 64 + g * 16 + jw * 4 + b;
      int idx = co * 256 + ci;
      int w = m1[idx] * (1 << s1[idx]);
      p |= (w & 0xFF) << (8 * b);
    }
    w1m[i] = p;
  }
  // w2m[((tap*4+s)*64+l)*4+jw]: conv2 B-frag per tap
  for (int i = t; i < 9216; i += nthr) {
    int jw = i & 3, l = (i >> 2) & 63;
    int rest = i >> 8;              // tap*4+s
    int s = rest & 3, tap = rest >> 2;
    int c = l & 15, g = l >> 4;
    int co = s * 16 + c;
    int ky = tap / 3, kx = tap - ky * 3;
    int p = 0;
    for (int b = 0; b < 4; ++b) {
      int ci = g * 16 + jw * 4 + b;
      int idx = ((co * 64 + ci) * 3 + ky) * 3 + kx;
      int w = m2[idx] * (1 << s2[idx]);
      p |= (w & 0xFF) << (8 * b);
    }
    w2m[i] = p;
  }
  // w3m[((s*4+nt)*64+l)*4+jw]: conv3 B-frag, co=s*64+nt*16+(l&15)
  for (int i = t; i < 4096; i += nthr) {
    int jw = i & 3, l = (i >> 2) & 63;
    int rest = i >> 8;              // s*4+nt
    int nt = rest & 3, s = rest >> 2;
    int c = l & 15, g = l >> 4;
    int co = s * 64 + nt * 16 + c;
    int p = 0;
    for (int b = 0; b < 4; ++b) {
      int ci = g * 16 + jw * 4 + b;
      int idx = co * 64 + ci;
      int w = m3[idx] * (1 << s3[idx]);
      p |= (w & 0xFF) << (8 * b);
    }
    w3m[i] = p;
  }
  for (int i = t; i < 64; i += nthr) {
    a1p[i] = a1[i];
    o1p[i] = __fmul_rn(b1[i], exp2f((float)q1[i] + 10.0f));
    a2p[i] = a2[i];
    o2p[i] = __fmul_rn(b2[i], exp2f((float)q2[i] + 10.0f));
  }
  for (int i = t; i < 256; i += nthr) {
    a3p[i] = a3[i];
    o3p[i] = __fmul_rn(b3[i], exp2f((float)q3[i] + 10.0f));
  }
}

// ---------------- k01: pack x -> int8 (x8p + LDS), then conv1 via MFMA ----------------
// (byte-identical to R15 — the pack runs exactly once per position here;
//  R16's halo-recompute fusion multiplied this phase by 3.6x and regressed.)
__global__ __launch_bounds__(256) void k01_pack_conv1(
    const float* __restrict__ x,
    const int* __restrict__ w1m,
    const float* __restrict__ a1p, const float* __restrict__ o1p,
    int* __restrict__ x8p, int* __restrict__ y1p)
{
  __shared__ int ldsx[64 * 68];   // 17408 B

  int tid = threadIdx.x;

  // ---- Phase A: load + pack ----
  {
    int o = tid & 3;
    int p = tid >> 2;
    size_t pg = (size_t)blockIdx.x * 64 + p;
    int n = (int)(pg / HW);
    int pos = (int)(pg - (size_t)n * HW);
    const float* xb = x + ((size_t)n * 256 + o * 64) * HW + pos;

    float f[64];
#pragma unroll
    for (int k = 0; k < 64; ++k) f[k] = xb[(size_t)k * HW];
    __builtin_amdgcn_sched_barrier(0);  // all 64 loads before any consumer

    int4 ov[4];
#pragma unroll
    for (int g = 0; g < 4; ++g) {
      int wds[4];
#pragma unroll
      for (int wdi = 0; wdi < 4; ++wdi) {
        int c0 = g * 16 + wdi * 4;
        wds[wdi] = ((int)f[c0] & 0xFF) | (((int)f[c0 + 1] & 0xFF) << 8) |
                   (((int)f[c0 + 2] & 0xFF) << 16) | (((int)f[c0 + 3] & 0xFF) << 24);
      }
      ov[g].x = wds[0]; ov[g].y = wds[1]; ov[g].z = wds[2]; ov[g].w = wds[3];
    }

    int* gb = x8p + pg * 64 + o * 16;
#pragma unroll
    for (int g = 0; g < 4; ++g) ((int4*)gb)[g] = ov[g];
    int* lb = &ldsx[p * 68 + o * 16];
#pragma unroll
    for (int g = 0; g < 4; ++g) *(int4*)(lb + g * 4) = ov[g];
  }
  __syncthreads();

  // ---- Phase B: conv1 MFMA ----
  int lane = tid & 63;
  int sW = __builtin_amdgcn_readfirstlane(tid >> 6);
  int c = lane & 15, g = lane >> 4;

  i32x4 acc[4];
#pragma unroll
  for (int mt = 0; mt < 4; ++mt) acc[mt] = (i32x4){0, 0, 0, 0};

#pragma unroll
  for (int kk = 0; kk < 4; ++kk) {
    i32x4 bf = *(const i32x4*)(w1m + ((kk * 4 + sW) * 64 + lane) * 4);
#pragma unroll
    for (int mt = 0; mt < 4; ++mt) {
      i32x4 af = *(const i32x4*)(ldsx + (mt * 16 + c) * 68 + kk * 16 + g * 4);
      acc[mt] = __builtin_amdgcn_mfma_i32_16x16x64_i8(af, bf, acc[mt], 0, 0, 0);
    }
  }

  float al = a1p[sW * 16 + c], of = o1p[sW * 16 + c];
  char* yb = (char*)y1p;
  size_t pb = (size_t)blockIdx.x * 64;
#pragma unroll
  for (int mt = 0; mt < 4; ++mt) {
#pragma unroll
    for (int r = 0; r < 4; ++r) {
      float rv = bnq(al, of, acc[mt][r]);
      int v = (int)rv;
      if (v < 0) v = 0;  // relu
      yb[(pb + mt * 16 + g * 4 + r) * 64 + sW * 16 + c] = (char)v;
    }
  }
}

// ---------------- k23: conv2 + conv3 via MFMA, 128-pos tiles ----------------
// R17 change vs R15: tile 64 -> 128 positions. Halo fan-out 3.6x -> 2.7x
// (6 rows x 58 staged once per 128 outputs), blocks 1568 -> 800, barriers
// and launch tails halved per output. After conv2 the halo region is dead
// and is reused (barrier-separated) for y2t + per-wave Dw. Tail block of
// each image (bl=24) is half-sized: block-uniform validB, clamped addresses.
__global__ __launch_bounds__(256) void k23_conv23(
    const int* __restrict__ y1p,
    const int* __restrict__ w2m,
    const float* __restrict__ a2p, const float* __restrict__ o2p,
    const int* __restrict__ w3m,
    const float* __restrict__ a3p, const float* __restrict__ o3p,
    const int* __restrict__ x8p,
    float* __restrict__ out)
{
  __shared__ __align__(16) char smem[30720];
  int4* halo = (int4*)smem;            // [348 pp][5 int4] = 27840 B (dead after conv2)
  char* y2t  = smem;                   // [128 pos][80 B] = 10240 B (aliases dead halo)
  // Dw: per-wave [64][20] ints at smem + 10240 + sW*5120 (aliases dead halo)

  // bijective XCD swizzle: 800 = 8*100; XCD k runs tiles 100k..100k+99
  int t0 = (blockIdx.x & 7) * 100 + (blockIdx.x >> 3);
  int n = t0 / 25, bl = t0 - n * 25;
  int p0l = bl * 128;
  int validB = (bl < 24);              // block-uniform: second 64-pos half valid
  int h0 = p0l / IMGW;

  int tid = threadIdx.x;
  int lane = tid & 63;
  int sW = __builtin_amdgcn_readfirstlane(tid >> 6);
  int c = lane & 15, g = lane >> 4;

  // ---- stage halo rows h0-1..h0+4 (6x58), zero-padded ----
  const int4* src = (const int4*)y1p;
#pragma unroll
  for (int i = 0; i < 6; ++i) {
    int idx = tid + i * 256;
    if (idx < 1392) {                  // 348 pp x 4 chunks
      int pp = idx >> 2, chunk = idx & 3;
      int r = pp / 58, col = pp - r * 58;
      int hh = h0 - 1 + r;
      int4 v = make_int4(0, 0, 0, 0);
      if ((unsigned)hh < 56u && col >= 1 && col <= 56)
        v = src[((size_t)n * HW + (size_t)hh * IMGW + (col - 1)) * 4 + chunk];
      halo[pp * 5 + chunk] = v;
    }
  }

  // ---- hoisted residual loads for both halves (in flight under conv2) ----
  size_t pgA = (size_t)n * HW + p0l + lane;
  size_t pgB = validB ? (pgA + 64) : pgA;     // clamped: always in-bounds
  const i32x4* ra = (const i32x4*)(x8p + pgA * 64 + sW * 16);
  const i32x4* rb = (const i32x4*)(x8p + pgB * 64 + sW * 16);
  i32x4 rqA0 = ra[0], rqA1 = ra[1], rqA2 = ra[2], rqA3 = ra[3];
  i32x4 rqB0 = rb[0], rqB1 = rb[1], rqB2 = rb[2], rqB3 = rb[3];

  __syncthreads();

  // M-tile centers (8 tiles x 16 pos = 128)
  int cen[8];
#pragma unroll
  for (int mt = 0; mt < 8; ++mt) {
    int pos = p0l + mt * 16 + c;
    int hh2 = pos / IMGW, ww2 = pos - hh2 * IMGW;
    cen[mt] = (hh2 - h0 + 1) * 58 + ww2 + 1;
  }

  // ---- conv2 MFMA: 9 taps x 8 M-tiles ----
  i32x4 acc2[8];
#pragma unroll
  for (int i = 0; i < 8; ++i) acc2[i] = (i32x4){0, 0, 0, 0};

#pragma unroll
  for (int tap = 0; tap < 9; ++tap) {
    i32x4 bf = *(const i32x4*)(w2m + ((tap * 4 + sW) * 64 + lane) * 4);
    int ky = tap / 3, kx = tap - ky * 3;
    int d = (ky - 1) * 58 + (kx - 1);
#pragma unroll
    for (int mt = 0; mt < 8; ++mt) {
      i32x4 af = *(const i32x4*)&halo[(cen[mt] + d) * 5 + g];
      acc2[mt] = __builtin_amdgcn_mfma_i32_16x16x64_i8(af, bf, acc2[mt], 0, 0, 0);
    }
  }
  __syncthreads();   // all halo reads done before y2t overwrites it

  // ---- conv2 BN+relu -> y2t ----
  {
    float al = a2p[sW * 16 + c], of = o2p[sW * 16 + c];
#pragma unroll
    for (int mt = 0; mt < 8; ++mt) {
#pragma unroll
      for (int r = 0; r < 4; ++r) {
        float rv = bnq(al, of, acc2[mt][r]);
        int v = (int)rv;
        if (v < 0) v = 0;
        y2t[(mt * 16 + g * 4 + r) * 80 + sW * 16 + c] = (char)v;
      }
    }
  }
  __syncthreads();

  // ---- conv3 MFMA + transpose-through-LDS epilogue, per 64-pos half ----
  int* Dw = (int*)(smem + 10240) + sW * 1280;  // per-wave [64 pos][20 ints]

#pragma unroll
  for (int ph = 0; ph < 2; ++ph) {
    if (ph == 1 && !validB) break;
    float* ob = out + (size_t)n * 256 * HW + p0l + ph * 64 + lane;
#pragma unroll
    for (int nt = 0; nt < 4; ++nt) {
      i32x4 bf = *(const i32x4*)(w3m + ((sW * 4 + nt) * 64 + lane) * 4);
#pragma unroll
      for (int mtl = 0; mtl < 4; ++mtl) {
        i32x4 af = *(const i32x4*)(y2t + ((ph * 4 + mtl) * 16 + c) * 80 + g * 16);
        i32x4 z = {0, 0, 0, 0};
        i32x4 D = __builtin_amdgcn_mfma_i32_16x16x64_i8(af, bf, z, 0, 0, 0);
        Dw[(mtl * 16 + g * 4 + 0) * 20 + c] = D[0];
        Dw[(mtl * 16 + g * 4 + 1) * 20 + c] = D[1];
        Dw[(mtl * 16 + g * 4 + 2) * 20 + c] = D[2];
        Dw[(mtl * 16 + g * 4 + 3) * 20 + c] = D[3];
      }
      // same-wave LDS write->read: ordered via lgkmcnt (compiler-inserted)
      i32x4 q0 = *(const i32x4*)(Dw + lane * 20 + 0);
      i32x4 q1 = *(const i32x4*)(Dw + lane * 20 + 4);
      i32x4 q2 = *(const i32x4*)(Dw + lane * 20 + 8);
      i32x4 q3 = *(const i32x4*)(Dw + lane * 20 + 12);
      i32x4 rqn;
      if (ph == 0) rqn = nt == 0 ? rqA0 : (nt == 1 ? rqA1 : (nt == 2 ? rqA2 : rqA3));
      else         rqn = nt == 0 ? rqB0 : (nt == 1 ? rqB1 : (nt == 2 ? rqB2 : rqB3));
#pragma unroll
      for (int cc = 0; cc < 16; ++cc) {
        int accv = cc < 4 ? q0[cc] : cc < 8 ? q1[cc - 4] : cc < 12 ? q2[cc - 8] : q3[cc - 12];
        int co = sW * 64 + nt * 16 + cc;          // wave-uniform -> s_load BN consts
        float rv = bnq(a3p[co], o3p[co], accv);
        int ip = rqn[cc >> 2];
        int id = (int)(int8_t)(ip >> (8 * (cc & 3)));
        int v = (int)rv + id;
        v = v > 127 ? 127 : v;
        v = v < 0 ? 0 : v;  // clamp(-128,..) then relu => max(0, min(127, .))
        ob[(size_t)co * HW] = (float)v;
      }
    }
  }
}

extern "C" void kernel_launch(void* const* d_in, const int* in_sizes, int n_in,
                              void* d_out, int out_size, void* d_ws, size_t ws_size,
                              hipStream_t stream) {
  const float* x  = (const float*)d_in[0];
  const int*   s1 = (const int*)d_in[1];
  const int*   m1 = (const int*)d_in[2];
  const float* a1 = (const float*)d_in[3];
  const float* b1 = (const float*)d_in[4];
  const int*   q1 = (const int*)d_in[5];
  const int*   s2 = (const int*)d_in[6];
  const int*   m2 = (const int*)d_in[7];
  const float* a2 = (const float*)d_in[8];
  const float* b2 = (const float*)d_in[9];
  const int*   q2 = (const int*)d_in[10];
  const int*   s3 = (const int*)d_in[11];
  const int*   m3 = (const int*)d_in[12];
  const float* a3 = (const float*)d_in[13];
  const float* b3 = (const float*)d_in[14];
  const int*   q3 = (const int*)d_in[15];

  char* ws = (char*)d_ws;
  int* w1m = (int*)(ws + 0);        // 16384 B
  int* w2m = (int*)(ws + 16384);    // 36864 B
  int* w3m = (int*)(ws + 53248);    // 16384 B
  float* a1p = (float*)(ws + 69632);
  float* o1p = (float*)(ws + 69888);
  float* a2p = (float*)(ws + 70144);
  float* o2p = (float*)(ws + 70400);
  float* a3p = (float*)(ws + 70656);
  float* o3p = (float*)(ws + 71680);
  int* y1p = (int*)(ws + 73728);                       // 6,422,528 B (packed [n][pos][16])
  int* x8p = (int*)(ws + 73728 + 6422528);             // 25,690,112 B (packed [n][pos][64])

  prep_kernel<<<64, 256, 0, stream>>>(s1, m1, a1, b1, q1,
                                      s2, m2, a2, b2, q2,
                                      s3, m3, a3, b3, q3,
                                      w1m, w2m, w3m,
                                      a1p, o1p, a2p, o2p, a3p, o3p);

  k01_pack_conv1<<<(NIMG * HW) / 64, 256, 0, stream>>>(x, w1m, a1p, o1p, x8p, y1p);
  // 25 tiles per image (24 x 128-pos + 1 x 64-pos), 32 images = 800 blocks
  k23_conv23<<<800, 256, 0, stream>>>(y1p, w2m, a2p, o2p,
                                      w3m, a3p, o3p, x8p,
                                      (float*)d_out);
}